// Round 8
// baseline (895.467 us; speedup 1.0000x reference)
//
#include <hip/hip_runtime.h>
#include <hip/hip_cooperative_groups.h>
#include <math.h>

namespace cg = cooperative_groups;

// Problem constants
#define BQ 8
#define SEQ 577
#define CH 768
#define NH 12
#define HD 64
#define M_ROWS (BQ * SEQ)      // 4616
#define QKV_CH (3 * CH)        // 2304
#define NX (M_ROWS * CH)       // 3545088
#define EPSF 1.1920929e-07f
#define F2P31 2147483648.0f    // float32(2^31 - 1) rounds to 2^31 -- replicate jnp

#define VT_ROW 640             // Vt row bytes (577 padded, 64B-aligned rows)
#define P_STRIDE 664           // P LDS row stride bytes

typedef __attribute__((ext_vector_type(4))) int i32x4;
typedef struct __align__(16) { long x, y; } L2T;

// shiftmax exp_int: bit-exact replication of reference f32 op sequence.
__device__ __forceinline__ float softmax_e(int svr, int mxr, float x0, float nx0) {
  float xi = (float)(svr - mxr);
  xi = xi + floorf(xi * 0.5f) - floorf(xi * 0.0625f);  // exact pow2 ops on ints
  xi = fmaxf(xi, nx0);
  float qd = floorf(xi / x0);                          // correctly-rounded fdiv, as ref
  float rr = xi - x0 * qd;
  int qi = (int)qd;                                    // in [0,15] for valid lanes
  float p2 = __int_as_float((142 - qi) << 23);         // 2^(15-qi) exact
  float e = floorf((rr * 0.5f - x0) * p2);
  return fmaxf(e, 0.0f);
}

// ---- shared MFMA accumulate: 128x128 block tile, wave w does 64x64, frags from global ----
__device__ __forceinline__ void mfma_gemm_core(
    const signed char* __restrict__ A, const signed char* __restrict__ Bm,
    int arow, int bcol, int c, int q, i32x4 acc[4][4]) {
  for (int k0 = 0; k0 < CH; k0 += 64) {
    L2T af[4], bf[4];
#pragma unroll
    for (int i = 0; i < 4; ++i)
      af[i] = *(const L2T*)(A + (size_t)(arow + i * 16 + c) * CH + k0 + q * 16);
#pragma unroll
    for (int j = 0; j < 4; ++j)
      bf[j] = *(const L2T*)(Bm + (size_t)(bcol + j * 16 + c) * CH + k0 + q * 16);
#pragma unroll
    for (int i = 0; i < 4; ++i)
#pragma unroll
      for (int j = 0; j < 4; ++j) {
        acc[i][j] = __builtin_amdgcn_mfma_i32_16x16x32_i8(af[i].x, bf[j].x, acc[i][j], 0, 0, 0);
        acc[i][j] = __builtin_amdgcn_mfma_i32_16x16x32_i8(af[i].y, bf[j].y, acc[i][j], 0, 0, 0);
      }
  }
}

// ---- block helpers (256 threads) ----
__device__ __forceinline__ void block_put_max(float v, float* red, int tid, float* dst) {
#pragma unroll
  for (int o = 32; o; o >>= 1) v = fmaxf(v, __shfl_xor(v, o, 64));
  __syncthreads();
  if ((tid & 63) == 0) red[tid >> 6] = v;
  __syncthreads();
  if (tid == 0) *dst = fmaxf(fmaxf(red[0], red[1]), fmaxf(red[2], red[3]));
}
__device__ __forceinline__ float block_get_max(const float* arr, int G, float* red, int tid) {
  float m = 0.f;
  for (int i = tid; i < G; i += 256) m = fmaxf(m, arr[i]);
#pragma unroll
  for (int o = 32; o; o >>= 1) m = fmaxf(m, __shfl_xor(m, o, 64));
  __syncthreads();
  if ((tid & 63) == 0) red[tid >> 6] = m;
  __syncthreads();
  return fmaxf(fmaxf(red[0], red[1]), fmaxf(red[2], red[3]));
}

// ================== MEGA KERNEL (cooperative, 7 phases, 6 grid syncs) ==================
__global__ __launch_bounds__(256, 4) void k_mega(
    const float* __restrict__ x, const float* __restrict__ w_qkv,
    const float* __restrict__ b_qkv, const float* __restrict__ w_proj,
    const float* __restrict__ b_proj, float* __restrict__ outp,
    signed char* __restrict__ WQ8, float* __restrict__ SWQ,
    signed char* __restrict__ WP8, float* __restrict__ SWP,
    signed char* __restrict__ X8, int* __restrict__ QKVI,
    signed char* __restrict__ Q8, signed char* __restrict__ K8,
    signed char* __restrict__ VT8, int* __restrict__ CTXI,
    signed char* __restrict__ C8,
    float* __restrict__ PM1, float* __restrict__ PM2, float* __restrict__ PM3) {
  cg::grid_group gg = cg::this_grid();
  __shared__ __align__(16) char SM[16 * P_STRIDE + 256 + 512 + 64];
  unsigned char* Pb = (unsigned char*)SM;
  int (*Rmax)[16] = (int(*)[16])(SM + 10624);
  double (*Rsum)[16] = (double(*)[16])(SM + 10624 + 256);
  float* red = (float*)(SM + 10624 + 256 + 512);

  const int tid = threadIdx.x, blk = blockIdx.x, G = gridDim.x;
  const int lane = tid & 63, wid = tid >> 6;
  const int NT = G * 256;
  const int gtid = blk * 256 + tid;
  const int cc = lane & 15, qq = lane >> 4;  // MFMA col / quad

  // ---------- P1: weight quant (one wave per row) + absmax(x) partials ----------
  {
    int gw = blk * 4 + wid, TW = G * 4;
    for (int row = gw; row < QKV_CH + CH; row += TW) {
      const float* wr; signed char* w8; float* sw; int r;
      if (row < QKV_CH) { r = row; wr = w_qkv + (size_t)r * CH; w8 = WQ8 + (size_t)r * CH; sw = SWQ; }
      else { r = row - QKV_CH; wr = w_proj + (size_t)r * CH; w8 = WP8 + (size_t)r * CH; sw = SWP; }
      float m = 0.f;
      for (int c = lane; c < CH; c += 64) m = fmaxf(m, fabsf(wr[c]));
#pragma unroll
      for (int o = 32; o; o >>= 1) m = fmaxf(m, __shfl_xor(m, o, 64));
      float s = fmaxf(m / 127.0f, EPSF);
      if (lane == 0) sw[r] = s;
      for (int c = lane; c < CH; c += 64) {
        float qv = rintf(wr[c] / s);
        qv = fminf(fmaxf(qv, -128.f), 127.f);
        w8[c] = (signed char)qv;
      }
    }
    float m = 0.f;
    for (int i = gtid; i < NX; i += NT) m = fmaxf(m, fabsf(x[i]));
    block_put_max(m, red, tid, &PM1[blk]);
    __threadfence();
    gg.sync();
  }

  // ---------- P2: activation quant ----------
  {
    float s_x = fmaxf(block_get_max(PM1, G, red, tid) / 127.0f, EPSF);
    for (int i = gtid; i < NX; i += NT) {
      float qv = rintf(x[i] / s_x);
      qv = fminf(fmaxf(qv, -128.f), 127.f);
      X8[i] = (signed char)qv;
    }
    __threadfence();
    gg.sync();
  }

  // ---------- P3: GEMM qkv (MFMA) + max|qkv_f| partials ----------
  {
    float s_x = fmaxf(block_get_max(PM1, G, red, tid) / 127.0f, EPSF);
    float lmax = 0.f;
    for (int ts = blk; ts < 18 * 37; ts += G) {
      int tx = ts % 18, ty = ts / 18;
      int arow = ty * 128 + (wid & 1) * 64;
      int bcol = tx * 128 + (wid >> 1) * 64;
      i32x4 acc[4][4] = {};
      mfma_gemm_core(X8, WQ8, arow, bcol, cc, qq, acc);
#pragma unroll
      for (int j = 0; j < 4; ++j) {
        int ccol = bcol + j * 16 + cc;
        float accs = s_x * SWQ[ccol];
        int bint = (int)rintf(b_qkv[ccol] / accs);
#pragma unroll
        for (int i = 0; i < 4; ++i)
#pragma unroll
          for (int r = 0; r < 4; ++r) {
            int rr = arow + i * 16 + qq * 4 + r;
            if (rr < M_ROWS) {
              int qv = acc[i][j][r] + bint;
              QKVI[(size_t)rr * QKV_CH + ccol] = qv;
              lmax = fmaxf(lmax, fabsf((float)qv * accs));
            }
          }
      }
    }
    block_put_max(lmax, red, tid, &PM2[blk]);
    __threadfence();
    gg.sync();
  }

  // ---------- P4: requant qkv -> Q8/K8 (linear) + VT8 (LDS-tiled transpose) ----------
  {
    float s_x = fmaxf(block_get_max(PM1, G, red, tid) / 127.0f, EPSF);
    float s_qkv = fmaxf(block_get_max(PM2, G, red, tid) / 127.0f, EPSF);
    // Q/K: o in [0,1536), coalesced both sides
    for (int j = gtid; j < M_ROWS * 1536; j += NT) {
      int bn = j / 1536;
      int o = j - bn * 1536;
      int qv = QKVI[(size_t)bn * QKV_CH + o];
      float accs = s_x * SWQ[o];
      float ns = accs / s_qkv;
      int e; float f = frexpf(ns, &e);
      float mm = floorf(f * F2P31 + 0.5f);
      float pw = __int_as_float((e + 96) << 23);   // 2^(e-31) exact
      float qf = (float)qv * accs;
      float z = rintf(qf / accs);
      float t8 = rintf((z * mm) * pw);
      t8 = fminf(fmaxf(t8, -128.f), 127.f);
      int isK = (o >= CH);
      int rem = o - (isK ? CH : 0);
      int h = rem >> 6, d = rem & 63;
      int b = bn / SEQ, n = bn - b * SEQ;
      size_t dst = (((size_t)(b * NH + h) * SEQ + n) << 6) + d;
      if (isK) K8[dst] = (signed char)t8; else Q8[dst] = (signed char)t8;
    }
    // V: (bh, 64n) tiles, transpose through LDS -> coalesced VT8 writes
    signed char* VTt = (signed char*)SM;  // 64 x 68 tile
    for (int vt = blk; vt < BQ * NH * 10; vt += G) {
      int bh = vt / 10, n0 = (vt - bh * 10) * 64;
      int b = bh / NH, h = bh - b * NH;
      int od = tid & 63;                       // d within head
      int o = 2 * CH + h * 64 + od;
      float accs = s_x * SWQ[o];
      float ns = accs / s_qkv;
      int e; float f = frexpf(ns, &e);
      float mm = floorf(f * F2P31 + 0.5f);
      float pw = __int_as_float((e + 96) << 23);
      int nr = tid >> 6;                       // 0..3
      __syncthreads();                         // protect LDS reuse across tiles
      for (int p = 0; p < 16; ++p) {
        int nl = nr * 16 + p;
        int n = n0 + nl;
        if (n < SEQ) {
          int qv = QKVI[(size_t)(b * SEQ + n) * QKV_CH + o];
          float qf = (float)qv * accs;
          float z = rintf(qf / accs);
          float t8 = rintf((z * mm) * pw);
          t8 = fminf(fmaxf(t8, -128.f), 127.f);
          VTt[od * 68 + nl] = (signed char)t8;
        }
      }
      __syncthreads();
      int w16 = tid & 15, dr = tid >> 4;
#pragma unroll
      for (int pp = 0; pp < 4; ++pp) {
        int d = pp * 16 + dr;
        int val = *(const int*)&VTt[d * 68 + w16 * 4];
        *(int*)(VT8 + (size_t)bh * (64 * VT_ROW) + (size_t)d * VT_ROW + n0 + w16 * 4) = val;
      }
    }
    __threadfence();
    gg.sync();
  }

  // ---------- P5: attention (grid-stride over (qt,bh) tiles) + max|ctx_f| partials ----------
  {
    float s_qkv = fmaxf(block_get_max(PM2, G, red, tid) / 127.0f, EPSF);
    float s_attn = (s_qkv * s_qkv) * 0.125f;
    float x0 = floorf(-1.0f / s_attn);
    float nx0 = 15.0f * x0;
    float pre_s = 0.0078125f * s_qkv;
    float avmax = 0.f;
    int col = cc, q4 = qq;
    // zero P pad bytes m in [576,640) once (stay zero; pack rewrites [576,592) w/ 0s)
    { int r = tid >> 4, w4 = tid & 15; *(int*)&Pb[r * P_STRIDE + 576 + (w4 << 2)] = 0; }
    for (int tt = blk; tt < 37 * BQ * NH; tt += G) {
      int qt = tt % 37, bh = tt / 37;
      int b = bh / NH, h = bh - b * NH;
      __syncthreads();  // previous tile's PV reads done before this tile's pack writes
      const signed char* Qb = Q8 + (((size_t)bh * SEQ + qt * 16 + col) << 6);
      long qa0 = *(const long*)(Qb + q4 * 8);
      long qa1 = *(const long*)(Qb + 32 + q4 * 8);
      const signed char* Kb = K8 + ((size_t)bh * SEQ << 6);
      int kt0 = (wid == 0) ? 0 : 10 + (wid - 1) * 9;
      int ktn = (wid == 0) ? 10 : 9;
      i32x4 sv[10];
      int mx[4] = {-2147483647 - 1, -2147483647 - 1, -2147483647 - 1, -2147483647 - 1};
#pragma unroll
      for (int u = 0; u < 10; ++u) {
        if (u < ktn) {
          int kt = kt0 + u;
          const signed char* kr = Kb + ((size_t)(kt * 16 + col) << 6);
          long kb0 = *(const long*)(kr + q4 * 8);
          long kb1 = *(const long*)(kr + 32 + q4 * 8);
          i32x4 a = {0, 0, 0, 0};
          a = __builtin_amdgcn_mfma_i32_16x16x32_i8(qa0, kb0, a, 0, 0, 0);
          a = __builtin_amdgcn_mfma_i32_16x16x32_i8(qa1, kb1, a, 0, 0, 0);
          sv[u] = a;
          bool valid = (kt < 36) | (col < 1);
#pragma unroll
          for (int r = 0; r < 4; ++r)
            if (valid) mx[r] = max(mx[r], a[r]);
        }
      }
#pragma unroll
      for (int r = 0; r < 4; ++r) {
        mx[r] = max(mx[r], __shfl_xor(mx[r], 1, 64));
        mx[r] = max(mx[r], __shfl_xor(mx[r], 2, 64));
        mx[r] = max(mx[r], __shfl_xor(mx[r], 4, 64));
        mx[r] = max(mx[r], __shfl_xor(mx[r], 8, 64));
      }
      if (col == 0) {
#pragma unroll
        for (int r = 0; r < 4; ++r) Rmax[wid][q4 * 4 + r] = mx[r];
      }
      __syncthreads();
#pragma unroll
      for (int r = 0; r < 4; ++r) {
        int row = q4 * 4 + r;
        mx[r] = max(max(Rmax[0][row], Rmax[1][row]), max(Rmax[2][row], Rmax[3][row]));
      }
      double ds[4] = {0.0, 0.0, 0.0, 0.0};
#pragma unroll
      for (int u = 0; u < 10; ++u) {
        if (u < ktn) {
          int kt = kt0 + u;
          bool valid = (kt < 36) | (col < 1);
#pragma unroll
          for (int r = 0; r < 4; ++r) {
            float e = softmax_e(sv[u][r], mx[r], x0, nx0);
            e = valid ? e : 0.0f;
            ds[r] += (double)e;   // exact integers -> order-free
            sv[u][r] = __float_as_int(e);
          }
        }
      }
#pragma unroll
      for (int r = 0; r < 4; ++r) {
        ds[r] += __shfl_xor(ds[r], 1, 64);
        ds[r] += __shfl_xor(ds[r], 2, 64);
        ds[r] += __shfl_xor(ds[r], 4, 64);
        ds[r] += __shfl_xor(ds[r], 8, 64);
      }
      if (col == 0) {
#pragma unroll
        for (int r = 0; r < 4; ++r) Rsum[wid][q4 * 4 + r] = ds[r];
      }
      __syncthreads();
      float fac[4];
#pragma unroll
      for (int r = 0; r < 4; ++r) {
        int row = q4 * 4 + r;
        double d = ((Rsum[0][row] + Rsum[1][row]) + Rsum[2][row]) + Rsum[3][row];
        float esum = fminf((float)d, F2P31);
        fac[r] = floorf(F2P31 / esum);
      }
#pragma unroll
      for (int u = 0; u < 10; ++u) {
        if (u < ktn) {
          int kt = kt0 + u;
#pragma unroll
          for (int r = 0; r < 4; ++r) {
            float e = __int_as_float(sv[u][r]);
            int p = (int)floorf((e * fac[r]) * 5.9604644775390625e-08f);  // /2^24 exact
            Pb[(q4 * 4 + r) * P_STRIDE + kt * 16 + col] = (unsigned char)p;
          }
        }
      }
      __syncthreads();
      const signed char* Vb = VT8 + (size_t)bh * (64 * VT_ROW);
      i32x4 acc = {0, 0, 0, 0};
      for (int mc = 0; mc < 20; ++mc) {
        long pa = *(const long*)&Pb[col * P_STRIDE + mc * 32 + q4 * 8];
        long vb = *(const long*)(Vb + (size_t)(wid * 16 + col) * VT_ROW + mc * 32 + q4 * 8);
        acc = __builtin_amdgcn_mfma_i32_16x16x32_i8(pa, vb, acc, 0, 0, 0);
      }
#pragma unroll
      for (int r = 0; r < 4; ++r) {
        int n = qt * 16 + q4 * 4 + r;
        if (n < SEQ) {
          int cacc = acc[r];
          CTXI[((size_t)(b * SEQ + n)) * CH + h * 64 + wid * 16 + col] = cacc;
          avmax = fmaxf(avmax, fabsf((float)cacc * pre_s));
        }
      }
    }
    block_put_max(avmax, red, tid, &PM3[blk]);
    __threadfence();
    gg.sync();
  }

  // ---------- P6: ctx requant ----------
  {
    float s_qkv = fmaxf(block_get_max(PM2, G, red, tid) / 127.0f, EPSF);
    float s_ctx = fmaxf(block_get_max(PM3, G, red, tid) / 127.0f, EPSF);
    float pre_s = 0.0078125f * s_qkv;
    float ns = pre_s / s_ctx;
    int e; float f = frexpf(ns, &e);
    float mm = floorf(f * F2P31 + 0.5f);
    float pw = __int_as_float((e + 96) << 23);
    for (int i = gtid; i < M_ROWS * CH; i += NT) {
      float cf = (float)CTXI[i] * pre_s;
      float z = rintf(cf / pre_s);
      float t8 = rintf((z * mm) * pw);
      t8 = fminf(fmaxf(t8, -128.f), 127.f);
      C8[i] = (signed char)t8;
    }
    __threadfence();
    gg.sync();
  }

  // ---------- P7: GEMM out (MFMA) ----------
  {
    float s_ctx = fmaxf(block_get_max(PM3, G, red, tid) / 127.0f, EPSF);
    for (int ts = blk; ts < 6 * 37; ts += G) {
      int tx = ts % 6, ty = ts / 6;
      int arow = ty * 128 + (wid & 1) * 64;
      int bcol = tx * 128 + (wid >> 1) * 64;
      i32x4 acc[4][4] = {};
      mfma_gemm_core(C8, WP8, arow, bcol, cc, qq, acc);
#pragma unroll
      for (int j = 0; j < 4; ++j) {
        int ccol = bcol + j * 16 + cc;
        float outs = s_ctx * SWP[ccol];
        int bint = (int)rintf(b_proj[ccol] / outs);
#pragma unroll
        for (int i = 0; i < 4; ++i)
#pragma unroll
          for (int r = 0; r < 4; ++r) {
            int rr = arow + i * 16 + qq * 4 + r;
            if (rr < M_ROWS)
              outp[(size_t)rr * CH + ccol] = (float)(acc[i][j][r] + bint) * outs;
          }
      }
    }
  }
}

// ================== FALLBACK KERNELS (R7 pipeline, used if coop launch fails) ==================
__global__ void k_absmax(const float* __restrict__ x, int n, unsigned* __restrict__ gmax) {
  float m = 0.f;
  int stride = gridDim.x * blockDim.x;
  for (int i = blockIdx.x * blockDim.x + threadIdx.x; i < n; i += stride)
    m = fmaxf(m, fabsf(x[i]));
#pragma unroll
  for (int off = 32; off; off >>= 1) m = fmaxf(m, __shfl_xor(m, off, 64));
  __shared__ float red[4];
  if ((threadIdx.x & 63) == 0) red[threadIdx.x >> 6] = m;
  __syncthreads();
  if (threadIdx.x == 0) {
    float mm = red[0];
    for (int i = 1; i < (int)(blockDim.x >> 6); ++i) mm = fmaxf(mm, red[i]);
    atomicMax(gmax, __float_as_uint(mm));
  }
}

__global__ void k_wquant(const float* __restrict__ w, int K,
                         signed char* __restrict__ w8, float* __restrict__ sw) {
  int row = blockIdx.x;
  const float* wr = w + (size_t)row * K;
  float m = 0.f;
  for (int c = threadIdx.x; c < K; c += blockDim.x) m = fmaxf(m, fabsf(wr[c]));
#pragma unroll
  for (int off = 32; off; off >>= 1) m = fmaxf(m, __shfl_xor(m, off, 64));
  __shared__ float red[4];
  if ((threadIdx.x & 63) == 0) red[threadIdx.x >> 6] = m;
  __syncthreads();
  float mm = fmaxf(fmaxf(red[0], red[1]), fmaxf(red[2], red[3]));
  float s = fmaxf(mm / 127.0f, EPSF);
  if (threadIdx.x == 0) sw[row] = s;
  for (int c = threadIdx.x; c < K; c += blockDim.x) {
    float q = rintf(wr[c] / s);
    q = fminf(fmaxf(q, -128.f), 127.f);
    w8[(size_t)row * K + c] = (signed char)q;
  }
}

__global__ void k_aquant(const float* __restrict__ x, int n,
                         const unsigned* __restrict__ hdr, signed char* __restrict__ x8) {
  float s = fmaxf(__uint_as_float(hdr[0]) / 127.0f, EPSF);
  int stride = gridDim.x * blockDim.x;
  for (int i = blockIdx.x * blockDim.x + threadIdx.x; i < n; i += stride) {
    float q = rintf(x[i] / s);
    q = fminf(fmaxf(q, -128.f), 127.f);
    x8[i] = (signed char)q;
  }
}

__global__ __launch_bounds__(256) void k_gemm_qkv(
    const signed char* __restrict__ A, const signed char* __restrict__ Bm,
    const float* __restrict__ swq, const float* __restrict__ bias,
    const unsigned* __restrict__ hdr, int* __restrict__ Cq, unsigned* __restrict__ gq) {
  __shared__ float red[4];
  int t = threadIdx.x;
  int lane = t & 63, w = t >> 6;
  int c = lane & 15, q = lane >> 4;
  int arow = blockIdx.y * 128 + (w & 1) * 64;
  int bcol = blockIdx.x * 128 + (w >> 1) * 64;
  i32x4 acc[4][4] = {};
  mfma_gemm_core(A, Bm, arow, bcol, c, q, acc);
  float s_x = fmaxf(__uint_as_float(hdr[0]) / 127.0f, EPSF);
  float lmax = 0.f;
#pragma unroll
  for (int j = 0; j < 4; ++j) {
    int ccol = bcol + j * 16 + c;
    float accs = s_x * swq[ccol];
    int bint = (int)rintf(bias[ccol] / accs);
#pragma unroll
    for (int i = 0; i < 4; ++i)
#pragma unroll
      for (int r = 0; r < 4; ++r) {
        int rr = arow + i * 16 + q * 4 + r;
        if (rr < M_ROWS) {
          int qv = acc[i][j][r] + bint;
          Cq[(size_t)rr * QKV_CH + ccol] = qv;
          lmax = fmaxf(lmax, fabsf((float)qv * accs));
        }
      }
  }
#pragma unroll
  for (int off = 32; off; off >>= 1) lmax = fmaxf(lmax, __shfl_xor(lmax, off, 64));
  if (lane == 0) red[w] = lmax;
  __syncthreads();
  if (t == 0)
    atomicMax(gq, __float_as_uint(fmaxf(fmaxf(red[0], red[1]), fmaxf(red[2], red[3]))));
}

__global__ void k_qkv_prep(const float* __restrict__ swq, const unsigned* __restrict__ hdr,
                           float* __restrict__ mq, float* __restrict__ pwq) {
  int o = blockIdx.x * blockDim.x + threadIdx.x;
  if (o >= QKV_CH) return;
  float s_x = fmaxf(__uint_as_float(hdr[0]) / 127.0f, EPSF);
  float s_qkv = fmaxf(__uint_as_float(hdr[1]) / 127.0f, EPSF);
  float ns = (s_x * swq[o]) / s_qkv;
  int e;
  float f = frexpf(ns, &e);
  mq[o] = floorf(f * F2P31 + 0.5f);
  pwq[o] = exp2f((float)e - 31.0f);
}

__global__ __launch_bounds__(256) void k_qkv_requant(
    const int* __restrict__ Cq, const float* __restrict__ swq,
    const float* __restrict__ mq, const float* __restrict__ pwq,
    const unsigned* __restrict__ hdr,
    signed char* __restrict__ Q8, signed char* __restrict__ K8,
    signed char* __restrict__ VT8) {
  float s_x = fmaxf(__uint_as_float(hdr[0]) / 127.0f, EPSF);
  int o = blockIdx.x * blockDim.x + threadIdx.x;
  int bn = blockIdx.y;
  float accs = s_x * swq[o];
  float qf = (float)Cq[(size_t)bn * QKV_CH + o] * accs;
  float z = rintf(qf / accs);
  float t8 = rintf((z * mq[o]) * pwq[o]);
  t8 = fminf(fmaxf(t8, -128.f), 127.f);
  int s = o / CH;
  int rem = o - s * CH;
  int h = rem >> 6, d = rem & 63;
  int b = bn / SEQ, n = bn - b * SEQ;
  int bh = b * NH + h;
  signed char v = (signed char)t8;
  if (s == 0) Q8[(((size_t)bh * SEQ + n) << 6) + d] = v;
  else if (s == 1) K8[(((size_t)bh * SEQ + n) << 6) + d] = v;
  else VT8[(size_t)bh * (64 * VT_ROW) + (size_t)d * VT_ROW + n] = v;
}

__global__ __launch_bounds__(256, 4) void k_attn(
    const signed char* __restrict__ Q8, const signed char* __restrict__ K8,
    const signed char* __restrict__ VT8, const unsigned* __restrict__ hdr,
    int* __restrict__ ctxi, unsigned* __restrict__ gctx) {
  __shared__ unsigned char P[16 * P_STRIDE];
  __shared__ int Rmax[4][16];
  __shared__ double Rsum[4][16];
  __shared__ float Rav[4];
  int tid = threadIdx.x;
  int t = tid & 63, wid = tid >> 6;
  int qt = blockIdx.x, bh = blockIdx.y;
  int b = bh / NH, h = bh - b * NH;
  int col = t & 15, q4 = t >> 4;
  {
    int r = tid >> 4, w4 = tid & 15;
    *(int*)&P[r * P_STRIDE + 576 + (w4 << 2)] = 0;
  }
  const signed char* Qb = Q8 + (((size_t)bh * SEQ + qt * 16 + col) << 6);
  long qa0 = *(const long*)(Qb + q4 * 8);
  long qa1 = *(const long*)(Qb + 32 + q4 * 8);
  const signed char* Kb = K8 + ((size_t)bh * SEQ << 6);
  int kt0 = (wid == 0) ? 0 : 10 + (wid - 1) * 9;
  int ktn = (wid == 0) ? 10 : 9;
  i32x4 sv[10];
  int mx[4] = {-2147483647 - 1, -2147483647 - 1, -2147483647 - 1, -2147483647 - 1};
#pragma unroll
  for (int u = 0; u < 10; ++u) {
    if (u < ktn) {
      int kt = kt0 + u;
      const signed char* kr = Kb + ((size_t)(kt * 16 + col) << 6);
      long kb0 = *(const long*)(kr + q4 * 8);
      long kb1 = *(const long*)(kr + 32 + q4 * 8);
      i32x4 a = {0, 0, 0, 0};
      a = __builtin_amdgcn_mfma_i32_16x16x32_i8(qa0, kb0, a, 0, 0, 0);
      a = __builtin_amdgcn_mfma_i32_16x16x32_i8(qa1, kb1, a, 0, 0, 0);
      sv[u] = a;
      bool valid = (kt < 36) | (col < 1);
#pragma unroll
      for (int r = 0; r < 4; ++r)
        if (valid) mx[r] = max(mx[r], a[r]);
    }
  }
#pragma unroll
  for (int r = 0; r < 4; ++r) {
    mx[r] = max(mx[r], __shfl_xor(mx[r], 1, 64));
    mx[r] = max(mx[r], __shfl_xor(mx[r], 2, 64));
    mx[r] = max(mx[r], __shfl_xor(mx[r], 4, 64));
    mx[r] = max(mx[r], __shfl_xor(mx[r], 8, 64));
  }
  if (col == 0) {
#pragma unroll
    for (int r = 0; r < 4; ++r) Rmax[wid][q4 * 4 + r] = mx[r];
  }
  __syncthreads();
#pragma unroll
  for (int r = 0; r < 4; ++r) {
    int row = q4 * 4 + r;
    mx[r] = max(max(Rmax[0][row], Rmax[1][row]), max(Rmax[2][row], Rmax[3][row]));
  }
  float s_qkv = fmaxf(__uint_as_float(hdr[1]) / 127.0f, EPSF);
  float s_attn = (s_qkv * s_qkv) * 0.125f;
  float x0 = floorf(-1.0f / s_attn);
  float nx0 = 15.0f * x0;
  double ds[4] = {0.0, 0.0, 0.0, 0.0};
#pragma unroll
  for (int u = 0; u < 10; ++u) {
    if (u < ktn) {
      int kt = kt0 + u;
      bool valid = (kt < 36) | (col < 1);
#pragma unroll
      for (int r = 0; r < 4; ++r) {
        float e = softmax_e(sv[u][r], mx[r], x0, nx0);
        e = valid ? e : 0.0f;
        ds[r] += (double)e;
        sv[u][r] = __float_as_int(e);
      }
    }
  }
#pragma unroll
  for (int r = 0; r < 4; ++r) {
    ds[r] += __shfl_xor(ds[r], 1, 64);
    ds[r] += __shfl_xor(ds[r], 2, 64);
    ds[r] += __shfl_xor(ds[r], 4, 64);
    ds[r] += __shfl_xor(ds[r], 8, 64);
  }
  if (col == 0) {
#pragma unroll
    for (int r = 0; r < 4; ++r) Rsum[wid][q4 * 4 + r] = ds[r];
  }
  __syncthreads();
  float fac[4];
#pragma unroll
  for (int r = 0; r < 4; ++r) {
    int row = q4 * 4 + r;
    double d = ((Rsum[0][row] + Rsum[1][row]) + Rsum[2][row]) + Rsum[3][row];
    float esum = fminf((float)d, F2P31);
    fac[r] = floorf(F2P31 / esum);
  }
#pragma unroll
  for (int u = 0; u < 10; ++u) {
    if (u < ktn) {
      int kt = kt0 + u;
#pragma unroll
      for (int r = 0; r < 4; ++r) {
        float e = __int_as_float(sv[u][r]);
        int p = (int)floorf((e * fac[r]) * 5.9604644775390625e-08f);
        P[(q4 * 4 + r) * P_STRIDE + kt * 16 + col] = (unsigned char)p;
      }
    }
  }
  __syncthreads();
  const signed char* Vb = VT8 + (size_t)bh * (64 * VT_ROW);
  i32x4 acc = {0, 0, 0, 0};
  for (int mc = 0; mc < 20; ++mc) {
    long pa = *(const long*)&P[col * P_STRIDE + mc * 32 + q4 * 8];
    long vb = *(const long*)(Vb + (size_t)(wid * 16 + col) * VT_ROW + mc * 32 + q4 * 8);
    acc = __builtin_amdgcn_mfma_i32_16x16x32_i8(pa, vb, acc, 0, 0, 0);
  }
  float pre_s = 0.0078125f * s_qkv;
  float avmax = 0.f;
#pragma unroll
  for (int r = 0; r < 4; ++r) {
    int n = qt * 16 + q4 * 4 + r;
    if (n < SEQ) {
      int cacc = acc[r];
      ctxi[((size_t)(b * SEQ + n)) * CH + h * 64 + wid * 16 + col] = cacc;
      avmax = fmaxf(avmax, fabsf((float)cacc * pre_s));
    }
  }
#pragma unroll
  for (int off = 32; off; off >>= 1) avmax = fmaxf(avmax, __shfl_xor(avmax, off, 64));
  if (t == 0) Rav[wid] = avmax;
  __syncthreads();
  if (tid == 0)
    atomicMax(gctx, __float_as_uint(fmaxf(fmaxf(Rav[0], Rav[1]), fmaxf(Rav[2], Rav[3]))));
}

__global__ void k_ctx_requant(const int* __restrict__ ctxi, const unsigned* __restrict__ hdr,
                              signed char* __restrict__ C8) {
  float s_qkv = fmaxf(__uint_as_float(hdr[1]) / 127.0f, EPSF);
  float pre_s = 0.0078125f * s_qkv;
  float s_ctx = fmaxf(__uint_as_float(hdr[2]) / 127.0f, EPSF);
  float ns = pre_s / s_ctx;
  int e;
  float f = frexpf(ns, &e);
  float mm = floorf(f * F2P31 + 0.5f);
  float pw = exp2f((float)e - 31.0f);
  int total = M_ROWS * CH;
  int stride = gridDim.x * blockDim.x;
  for (int i = blockIdx.x * blockDim.x + threadIdx.x; i < total; i += stride) {
    float cf = (float)ctxi[i] * pre_s;
    float z = rintf(cf / pre_s);
    float t8 = rintf((z * mm) * pw);
    t8 = fminf(fmaxf(t8, -128.f), 127.f);
    C8[i] = (signed char)t8;
  }
}

__global__ __launch_bounds__(256) void k_gemm_out(
    const signed char* __restrict__ A, const signed char* __restrict__ Bm,
    const float* __restrict__ swp, const float* __restrict__ bias,
    const unsigned* __restrict__ hdr, float* __restrict__ outp) {
  int t = threadIdx.x;
  int lane = t & 63, w = t >> 6;
  int c = lane & 15, q = lane >> 4;
  int arow = blockIdx.y * 128 + (w & 1) * 64;
  int bcol = blockIdx.x * 128 + (w >> 1) * 64;
  i32x4 acc[4][4] = {};
  mfma_gemm_core(A, Bm, arow, bcol, c, q, acc);
  float s_ctx = fmaxf(__uint_as_float(hdr[2]) / 127.0f, EPSF);
#pragma unroll
  for (int j = 0; j < 4; ++j) {
    int ccol = bcol + j * 16 + c;
    float outs = s_ctx * swp[ccol];
    int bint = (int)rintf(bias[ccol] / outs);
#pragma unroll
    for (int i = 0; i < 4; ++i)
#pragma unroll
      for (int r = 0; r < 4; ++r) {
        int rr = arow + i * 16 + q * 4 + r;
        if (rr < M_ROWS)
          outp[(size_t)rr * CH + ccol] = (float)(acc[i][j][r] + bint) * outs;
      }
  }
}

extern "C" void kernel_launch(void* const* d_in, const int* in_sizes, int n_in,
                              void* d_out, int out_size, void* d_ws, size_t ws_size,
                              hipStream_t stream) {
  const float* x = (const float*)d_in[0];
  const float* w_qkv = (const float*)d_in[1];
  const float* b_qkv = (const float*)d_in[2];
  const float* w_proj = (const float*)d_in[3];
  const float* b_proj = (const float*)d_in[4];
  float* outp = (float*)d_out;

  // ---- workspace: bump allocator, 4 KB aligned ----
  char* ws = (char*)d_ws;
  size_t off = 0;
  auto alloc = [&](size_t sz) -> char* {
    char* p = ws + off;
    off = (off + sz + 4095) & ~(size_t)4095;
    return p;
  };
  unsigned* hdr = (unsigned*)alloc(256);
  float* SWQ = (float*)alloc(QKV_CH * 4);
  float* SWP = (float*)alloc(CH * 4);
  float* MQ  = (float*)alloc(QKV_CH * 4);
  float* PWQ = (float*)alloc(QKV_CH * 4);
  float* PM1 = (float*)alloc(2048 * 4);
  float* PM2 = (float*)alloc(2048 * 4);
  float* PM3 = (float*)alloc(2048 * 4);
  signed char* WQ8 = (signed char*)alloc((size_t)QKV_CH * CH);
  signed char* WP8 = (signed char*)alloc((size_t)CH * CH);
  signed char* X8  = (signed char*)alloc((size_t)(M_ROWS + 128) * CH);
  signed char* Q8  = (signed char*)alloc((size_t)M_ROWS * CH);
  signed char* K8  = (signed char*)alloc((size_t)M_ROWS * CH);
  signed char* VT8 = (signed char*)alloc((size_t)BQ * NH * 64 * VT_ROW);
  signed char* C8  = (signed char*)alloc((size_t)(M_ROWS + 128) * CH);
  int* QKVI = (int*)alloc((size_t)M_ROWS * QKV_CH * 4);
  int* CTXI = (int*)alloc((size_t)M_ROWS * CH * 4);
  (void)ws_size;

  // ---- try cooperative mega-kernel (1 dispatch); fall back to R7 pipeline ----
  bool coop_ok = false;
  int nb = 0;
  if (hipOccupancyMaxActiveBlocksPerMultiprocessor(&nb, (const void*)k_mega, 256, 0)
          == hipSuccess && nb > 0) {
    int gblk = nb * 256;            // 256 CUs on MI355X
    if (gblk > 1024) gblk = 1024;
    void* margs[] = {
      (void*)&x, (void*)&w_qkv, (void*)&b_qkv, (void*)&w_proj, (void*)&b_proj,
      (void*)&outp,
      (void*)&WQ8, (void*)&SWQ, (void*)&WP8, (void*)&SWP,
      (void*)&X8, (void*)&QKVI, (void*)&Q8, (void*)&K8, (void*)&VT8,
      (void*)&CTXI, (void*)&C8, (void*)&PM1, (void*)&PM2, (void*)&PM3
    };
    hipError_t e = hipLaunchCooperativeKernel((const void*)k_mega, dim3(gblk), dim3(256),
                                              margs, 0, stream);
    coop_ok = (e == hipSuccess);
    if (!coop_ok) (void)hipGetLastError();  // clear sticky error before fallback
  }

  if (!coop_ok) {
    hipMemsetAsync(hdr, 0, 256, stream);
    int nx = NX;
    k_absmax<<<1024, 256, 0, stream>>>(x, nx, hdr + 0);
    k_wquant<<<QKV_CH, 256, 0, stream>>>(w_qkv, CH, WQ8, SWQ);
    k_wquant<<<CH, 256, 0, stream>>>(w_proj, CH, WP8, SWP);
    k_aquant<<<2048, 256, 0, stream>>>(x, nx, hdr, X8);
    dim3 g1(QKV_CH / 128, (M_ROWS + 127) / 128);
    k_gemm_qkv<<<g1, 256, 0, stream>>>(X8, WQ8, SWQ, b_qkv, hdr, QKVI, hdr + 1);
    k_qkv_prep<<<(QKV_CH + 255) / 256, 256, 0, stream>>>(SWQ, hdr, MQ, PWQ);
    dim3 gr(QKV_CH / 256, M_ROWS);
    k_qkv_requant<<<gr, 256, 0, stream>>>(QKVI, SWQ, MQ, PWQ, hdr, Q8, K8, VT8);
    dim3 ga(37, BQ * NH);
    k_attn<<<ga, 256, 0, stream>>>(Q8, K8, VT8, hdr, CTXI, hdr + 2);
    k_ctx_requant<<<2048, 256, 0, stream>>>(CTXI, hdr, C8);
    dim3 g2(CH / 128, (M_ROWS + 127) / 128);
    k_gemm_out<<<g2, 256, 0, stream>>>(C8, WP8, SWP, b_proj, hdr, outp);
  }
}

// Round 9
// 250.448 us; speedup vs baseline: 3.5755x; 3.5755x over previous
//
#include <hip/hip_runtime.h>
#include <math.h>

// Problem constants
#define BQ 8
#define SEQ 577
#define CH 768
#define NH 12
#define HD 64
#define M_ROWS (BQ * SEQ)      // 4616
#define QKV_CH (3 * CH)        // 2304
#define NX (M_ROWS * CH)       // 3545088
#define EPSF 1.1920929e-07f
#define F2P31 2147483648.0f    // float32(2^31 - 1) rounds to 2^31 -- replicate jnp

#define VT_ROW 640             // Vt row bytes (577 padded, 64B-aligned rows)
#define P_STRIDE 664           // P LDS row stride bytes

typedef __attribute__((ext_vector_type(4))) int i32x4;
typedef struct __align__(16) { long x, y; } L2T;

// shiftmax exp_int: bit-exact replication of reference f32 op sequence.
__device__ __forceinline__ float softmax_e(int svr, int mxr, float x0, float nx0) {
  float xi = (float)(svr - mxr);
  xi = xi + floorf(xi * 0.5f) - floorf(xi * 0.0625f);  // exact pow2 ops on ints
  xi = fmaxf(xi, nx0);
  float qd = floorf(xi / x0);                          // correctly-rounded fdiv, as ref
  float rr = xi - x0 * qd;
  int qi = (int)qd;                                    // in [0,15] for valid lanes
  float p2 = __int_as_float((142 - qi) << 23);         // 2^(15-qi) exact
  float e = floorf((rr * 0.5f - x0) * p2);
  return fmaxf(e, 0.0f);
}

// ---- shared MFMA accumulate: 128x128 block tile, wave w does 64x64, frags from global ----
__device__ __forceinline__ void mfma_gemm_core(
    const signed char* __restrict__ A, const signed char* __restrict__ Bm,
    int arow, int bcol, int c, int q, i32x4 acc[4][4]) {
  for (int k0 = 0; k0 < CH; k0 += 64) {
    L2T af[4], bf[4];
#pragma unroll
    for (int i = 0; i < 4; ++i)
      af[i] = *(const L2T*)(A + (size_t)(arow + i * 16 + c) * CH + k0 + q * 16);
#pragma unroll
    for (int j = 0; j < 4; ++j)
      bf[j] = *(const L2T*)(Bm + (size_t)(bcol + j * 16 + c) * CH + k0 + q * 16);
#pragma unroll
    for (int i = 0; i < 4; ++i)
#pragma unroll
      for (int j = 0; j < 4; ++j) {
        acc[i][j] = __builtin_amdgcn_mfma_i32_16x16x32_i8(af[i].x, bf[j].x, acc[i][j], 0, 0, 0);
        acc[i][j] = __builtin_amdgcn_mfma_i32_16x16x32_i8(af[i].y, bf[j].y, acc[i][j], 0, 0, 0);
      }
  }
}

// ---------------- fused prep: blocks [0,3072) weight-quant rows; [3072,4096) absmax(x) ----
__global__ __launch_bounds__(256) void k_prep(
    const float* __restrict__ x, const float* __restrict__ w_qkv,
    const float* __restrict__ w_proj,
    signed char* __restrict__ WQ8, float* __restrict__ SWQ,
    signed char* __restrict__ WP8, float* __restrict__ SWP,
    unsigned* __restrict__ gmax) {
  __shared__ float red[4];
  int blk = blockIdx.x, tid = threadIdx.x;
  if (blk < QKV_CH + CH) {
    const float* wr; signed char* w8; float* sw; int r;
    if (blk < QKV_CH) { r = blk; wr = w_qkv + (size_t)r * CH; w8 = WQ8 + (size_t)r * CH; sw = SWQ; }
    else { r = blk - QKV_CH; wr = w_proj + (size_t)r * CH; w8 = WP8 + (size_t)r * CH; sw = SWP; }
    float m = 0.f;
    for (int c = tid; c < CH; c += 256) m = fmaxf(m, fabsf(wr[c]));
#pragma unroll
    for (int o = 32; o; o >>= 1) m = fmaxf(m, __shfl_xor(m, o, 64));
    if ((tid & 63) == 0) red[tid >> 6] = m;
    __syncthreads();
    float mm = fmaxf(fmaxf(red[0], red[1]), fmaxf(red[2], red[3]));
    float s = fmaxf(mm / 127.0f, EPSF);
    if (tid == 0) sw[r] = s;
    for (int c = tid; c < CH; c += 256) {
      float q = rintf(wr[c] / s);
      q = fminf(fmaxf(q, -128.f), 127.f);
      w8[c] = (signed char)q;
    }
  } else {
    int ab = blk - (QKV_CH + CH);            // [0,1024)
    float m = 0.f;
    for (int i = ab * 256 + tid; i < NX; i += 1024 * 256) m = fmaxf(m, fabsf(x[i]));
#pragma unroll
    for (int o = 32; o; o >>= 1) m = fmaxf(m, __shfl_xor(m, o, 64));
    if ((tid & 63) == 0) red[tid >> 6] = m;
    __syncthreads();
    if (tid == 0)
      atomicMax(gmax, __float_as_uint(fmaxf(fmaxf(red[0], red[1]), fmaxf(red[2], red[3]))));
  }
}

// ---------------- per-tensor activation quant ----------------
__global__ void k_aquant(const float* __restrict__ x, int n,
                         const unsigned* __restrict__ hdr, signed char* __restrict__ x8) {
  float s = fmaxf(__uint_as_float(hdr[0]) / 127.0f, EPSF);
  int stride = gridDim.x * blockDim.x;
  for (int i = blockIdx.x * blockDim.x + threadIdx.x; i < n; i += stride) {
    float q = rintf(x[i] / s);
    q = fminf(fmaxf(q, -128.f), 127.f);
    x8[i] = (signed char)q;
  }
}

// ---------------- GEMM1 (MFMA): qkv_int = X8*WQ8^T + rint(bias/acc_s); track max|qkv_f| ----
__global__ __launch_bounds__(256) void k_gemm_qkv(
    const signed char* __restrict__ A, const signed char* __restrict__ Bm,
    const float* __restrict__ swq, const float* __restrict__ bias,
    const unsigned* __restrict__ hdr, int* __restrict__ Cq, unsigned* __restrict__ gq) {
  __shared__ float red[4];
  int t = threadIdx.x;
  int lane = t & 63, w = t >> 6;
  int c = lane & 15, q = lane >> 4;
  int arow = blockIdx.y * 128 + (w & 1) * 64;
  int bcol = blockIdx.x * 128 + (w >> 1) * 64;
  i32x4 acc[4][4] = {};
  mfma_gemm_core(A, Bm, arow, bcol, c, q, acc);
  float s_x = fmaxf(__uint_as_float(hdr[0]) / 127.0f, EPSF);
  float lmax = 0.f;
#pragma unroll
  for (int j = 0; j < 4; ++j) {
    int ccol = bcol + j * 16 + c;
    float accs = s_x * swq[ccol];
    int bint = (int)rintf(bias[ccol] / accs);
#pragma unroll
    for (int i = 0; i < 4; ++i)
#pragma unroll
      for (int r = 0; r < 4; ++r) {
        int rr = arow + i * 16 + q * 4 + r;
        if (rr < M_ROWS) {
          int qv = acc[i][j][r] + bint;
          Cq[(size_t)rr * QKV_CH + ccol] = qv;
          lmax = fmaxf(lmax, fabsf((float)qv * accs));
        }
      }
  }
#pragma unroll
  for (int off = 32; off; off >>= 1) lmax = fmaxf(lmax, __shfl_xor(lmax, off, 64));
  if (lane == 0) red[w] = lmax;
  __syncthreads();
  if (t == 0)
    atomicMax(gq, __float_as_uint(fmaxf(fmaxf(red[0], red[1]), fmaxf(red[2], red[3]))));
}

// ---- requant qkv -> Q8/K8 (linear, blocks [0,4096)) + VT8 (LDS transpose, blocks [4096,5056)) ----
#define NQKB 4096
__global__ __launch_bounds__(256) void k_qkv_requant(
    const int* __restrict__ Cq, const float* __restrict__ swq,
    const unsigned* __restrict__ hdr,
    signed char* __restrict__ Q8, signed char* __restrict__ K8,
    signed char* __restrict__ VT8) {
  float s_x = fmaxf(__uint_as_float(hdr[0]) / 127.0f, EPSF);
  float s_qkv = fmaxf(__uint_as_float(hdr[1]) / 127.0f, EPSF);
  int blk = blockIdx.x, tid = threadIdx.x;
  if (blk < NQKB) {
    // Q/K: o in [0,1536): coalesced read + write
    for (int j = blk * 256 + tid; j < M_ROWS * 1536; j += NQKB * 256) {
      int bn = j / 1536;
      int o = j - bn * 1536;
      int qv = Cq[(size_t)bn * QKV_CH + o];
      float accs = s_x * swq[o];
      float ns = accs / s_qkv;
      int e; float f = frexpf(ns, &e);
      float mm = floorf(f * F2P31 + 0.5f);
      float pw = __int_as_float((e + 96) << 23);   // 2^(e-31) exact
      float qf = (float)qv * accs;
      float z = rintf(qf / accs);
      float t8 = rintf((z * mm) * pw);
      t8 = fminf(fmaxf(t8, -128.f), 127.f);
      int isK = (o >= CH);
      int rem = o - (isK ? CH : 0);
      int h = rem >> 6, d = rem & 63;
      int b = bn / SEQ, n = bn - b * SEQ;
      size_t dst = (((size_t)(b * NH + h) * SEQ + n) << 6) + d;
      if (isK) K8[dst] = (signed char)t8; else Q8[dst] = (signed char)t8;
    }
  } else {
    // V: one (bh, 64-n) tile per block, transpose through LDS -> coalesced VT8 writes
    __shared__ signed char VTt[64 * 68];
    int vt = blk - NQKB;                     // [0, 960)
    int bh = vt / 10, n0 = (vt - bh * 10) * 64;
    int b = bh / NH, h = bh - b * NH;
    int od = tid & 63;                       // d within head
    int o = 2 * CH + h * 64 + od;
    float accs = s_x * swq[o];
    float ns = accs / s_qkv;
    int e; float f = frexpf(ns, &e);
    float mm = floorf(f * F2P31 + 0.5f);
    float pw = __int_as_float((e + 96) << 23);
    int nr = tid >> 6;                       // 0..3
    for (int p = 0; p < 16; ++p) {
      int nl = nr * 16 + p;
      int n = n0 + nl;
      signed char v = 0;
      if (n < SEQ) {
        int qv = Cq[(size_t)(b * SEQ + n) * QKV_CH + o];
        float qf = (float)qv * accs;
        float z = rintf(qf / accs);
        float t8 = rintf((z * mm) * pw);
        t8 = fminf(fmaxf(t8, -128.f), 127.f);
        v = (signed char)t8;
      }
      VTt[od * 68 + nl] = v;
    }
    __syncthreads();
    int w16 = tid & 15, dr = tid >> 4;
#pragma unroll
    for (int pp = 0; pp < 4; ++pp) {
      int d = pp * 16 + dr;
      int val = *(const int*)&VTt[d * 68 + w16 * 4];
      *(int*)(VT8 + (size_t)bh * (64 * VT_ROW) + (size_t)d * VT_ROW + n0 + w16 * 4) = val;
    }
  }
}

// ---- attention: 256-thr block per (qt, bh); 4 waves split 37 kv-tiles; single pass ----
__global__ __launch_bounds__(256, 8) void k_attn(
    const signed char* __restrict__ Q8, const signed char* __restrict__ K8,
    const signed char* __restrict__ VT8, const unsigned* __restrict__ hdr,
    int* __restrict__ ctxi, unsigned* __restrict__ gctx) {
  __shared__ unsigned char P[16 * P_STRIDE];   // probs [row][m]
  __shared__ int Rmax[4][16];
  __shared__ double Rsum[4][16];
  __shared__ float Rav[4];
  int tid = threadIdx.x;
  int t = tid & 63, wid = tid >> 6;
  int qt = blockIdx.x, bh = blockIdx.y;
  int b = bh / NH, h = bh - b * NH;
  int col = t & 15, q4 = t >> 4;
  {
    int r = tid >> 4, w4 = tid & 15;
    *(int*)&P[r * P_STRIDE + 576 + (w4 << 2)] = 0;
  }
  const signed char* Qb = Q8 + (((size_t)bh * SEQ + qt * 16 + col) << 6);
  long qa0 = *(const long*)(Qb + q4 * 8);
  long qa1 = *(const long*)(Qb + 32 + q4 * 8);
  const signed char* Kb = K8 + ((size_t)bh * SEQ << 6);
  int kt0 = (wid == 0) ? 0 : 10 + (wid - 1) * 9;
  int ktn = (wid == 0) ? 10 : 9;
  i32x4 sv[10];
  int mx[4] = {-2147483647 - 1, -2147483647 - 1, -2147483647 - 1, -2147483647 - 1};
#pragma unroll
  for (int u = 0; u < 10; ++u) {
    if (u < ktn) {
      int kt = kt0 + u;
      const signed char* kr = Kb + ((size_t)(kt * 16 + col) << 6);
      long kb0 = *(const long*)(kr + q4 * 8);
      long kb1 = *(const long*)(kr + 32 + q4 * 8);
      i32x4 a = {0, 0, 0, 0};
      a = __builtin_amdgcn_mfma_i32_16x16x32_i8(qa0, kb0, a, 0, 0, 0);
      a = __builtin_amdgcn_mfma_i32_16x16x32_i8(qa1, kb1, a, 0, 0, 0);
      sv[u] = a;
      bool valid = (kt < 36) | (col < 1);
#pragma unroll
      for (int r = 0; r < 4; ++r)
        if (valid) mx[r] = max(mx[r], a[r]);
    }
  }
#pragma unroll
  for (int r = 0; r < 4; ++r) {
    mx[r] = max(mx[r], __shfl_xor(mx[r], 1, 64));
    mx[r] = max(mx[r], __shfl_xor(mx[r], 2, 64));
    mx[r] = max(mx[r], __shfl_xor(mx[r], 4, 64));
    mx[r] = max(mx[r], __shfl_xor(mx[r], 8, 64));
  }
  if (col == 0) {
#pragma unroll
    for (int r = 0; r < 4; ++r) Rmax[wid][q4 * 4 + r] = mx[r];
  }
  __syncthreads();
#pragma unroll
  for (int r = 0; r < 4; ++r) {
    int row = q4 * 4 + r;
    mx[r] = max(max(Rmax[0][row], Rmax[1][row]), max(Rmax[2][row], Rmax[3][row]));
  }
  float s_qkv = fmaxf(__uint_as_float(hdr[1]) / 127.0f, EPSF);
  float s_attn = (s_qkv * s_qkv) * 0.125f;
  float x0 = floorf(-1.0f / s_attn);
  float nx0 = 15.0f * x0;
  double ds[4] = {0.0, 0.0, 0.0, 0.0};
#pragma unroll
  for (int u = 0; u < 10; ++u) {
    if (u < ktn) {
      int kt = kt0 + u;
      bool valid = (kt < 36) | (col < 1);
#pragma unroll
      for (int r = 0; r < 4; ++r) {
        float e = softmax_e(sv[u][r], mx[r], x0, nx0);
        e = valid ? e : 0.0f;
        ds[r] += (double)e;   // exact integers -> order-free
        sv[u][r] = __float_as_int(e);
      }
    }
  }
#pragma unroll
  for (int r = 0; r < 4; ++r) {
    ds[r] += __shfl_xor(ds[r], 1, 64);
    ds[r] += __shfl_xor(ds[r], 2, 64);
    ds[r] += __shfl_xor(ds[r], 4, 64);
    ds[r] += __shfl_xor(ds[r], 8, 64);
  }
  if (col == 0) {
#pragma unroll
    for (int r = 0; r < 4; ++r) Rsum[wid][q4 * 4 + r] = ds[r];
  }
  __syncthreads();
  float fac[4];
#pragma unroll
  for (int r = 0; r < 4; ++r) {
    int row = q4 * 4 + r;
    double d = ((Rsum[0][row] + Rsum[1][row]) + Rsum[2][row]) + Rsum[3][row];
    float esum = fminf((float)d, F2P31);
    fac[r] = floorf(F2P31 / esum);
  }
#pragma unroll
  for (int u = 0; u < 10; ++u) {
    if (u < ktn) {
      int kt = kt0 + u;
#pragma unroll
      for (int r = 0; r < 4; ++r) {
        float e = __int_as_float(sv[u][r]);
        int p = (int)floorf((e * fac[r]) * 5.9604644775390625e-08f);  // /2^24 exact
        P[(q4 * 4 + r) * P_STRIDE + kt * 16 + col] = (unsigned char)p;
      }
    }
  }
  __syncthreads();
  const signed char* Vb = VT8 + (size_t)bh * (64 * VT_ROW);
  i32x4 acc = {0, 0, 0, 0};
  for (int mc = 0; mc < 20; ++mc) {
    long pa = *(const long*)&P[col * P_STRIDE + mc * 32 + q4 * 8];
    long vb = *(const long*)(Vb + (size_t)(wid * 16 + col) * VT_ROW + mc * 32 + q4 * 8);
    acc = __builtin_amdgcn_mfma_i32_16x16x32_i8(pa, vb, acc, 0, 0, 0);
  }
  float pre_s = 0.0078125f * s_qkv;
  float avmax = 0.f;
#pragma unroll
  for (int r = 0; r < 4; ++r) {
    int n = qt * 16 + q4 * 4 + r;
    if (n < SEQ) {
      int cacc = acc[r];
      ctxi[((size_t)(b * SEQ + n)) * CH + h * 64 + wid * 16 + col] = cacc;
      avmax = fmaxf(avmax, fabsf((float)cacc * pre_s));
    }
  }
#pragma unroll
  for (int off = 32; off; off >>= 1) avmax = fmaxf(avmax, __shfl_xor(avmax, off, 64));
  if (t == 0) Rav[wid] = avmax;
  __syncthreads();
  if (tid == 0)
    atomicMax(gctx, __float_as_uint(fmaxf(fmaxf(Rav[0], Rav[1]), fmaxf(Rav[2], Rav[3]))));
}

// ---------------- requant ctx -> int8 ----------------
__global__ void k_ctx_requant(const int* __restrict__ ctxi, const unsigned* __restrict__ hdr,
                              signed char* __restrict__ C8) {
  float s_qkv = fmaxf(__uint_as_float(hdr[1]) / 127.0f, EPSF);
  float pre_s = 0.0078125f * s_qkv;
  float s_ctx = fmaxf(__uint_as_float(hdr[2]) / 127.0f, EPSF);
  float ns = pre_s / s_ctx;
  int e;
  float f = frexpf(ns, &e);
  float mm = floorf(f * F2P31 + 0.5f);
  float pw = exp2f((float)e - 31.0f);
  int total = M_ROWS * CH;
  int stride = gridDim.x * blockDim.x;
  for (int i = blockIdx.x * blockDim.x + threadIdx.x; i < total; i += stride) {
    float cf = (float)ctxi[i] * pre_s;
    float z = rintf(cf / pre_s);
    float t8 = rintf((z * mm) * pw);
    t8 = fminf(fmaxf(t8, -128.f), 127.f);
    C8[i] = (signed char)t8;
  }
}

// ---------------- GEMM2 (MFMA): out = (C8*WP8^T + rint(b/out_s)) * out_s ----------------
__global__ __launch_bounds__(256) void k_gemm_out(
    const signed char* __restrict__ A, const signed char* __restrict__ Bm,
    const float* __restrict__ swp, const float* __restrict__ bias,
    const unsigned* __restrict__ hdr, float* __restrict__ outp) {
  int t = threadIdx.x;
  int lane = t & 63, w = t >> 6;
  int c = lane & 15, q = lane >> 4;
  int arow = blockIdx.y * 128 + (w & 1) * 64;
  int bcol = blockIdx.x * 128 + (w >> 1) * 64;
  i32x4 acc[4][4] = {};
  mfma_gemm_core(A, Bm, arow, bcol, c, q, acc);
  float s_ctx = fmaxf(__uint_as_float(hdr[2]) / 127.0f, EPSF);
#pragma unroll
  for (int j = 0; j < 4; ++j) {
    int ccol = bcol + j * 16 + c;
    float outs = s_ctx * swp[ccol];
    int bint = (int)rintf(bias[ccol] / outs);
#pragma unroll
    for (int i = 0; i < 4; ++i)
#pragma unroll
      for (int r = 0; r < 4; ++r) {
        int rr = arow + i * 16 + q * 4 + r;
        if (rr < M_ROWS)
          outp[(size_t)rr * CH + ccol] = (float)(acc[i][j][r] + bint) * outs;
      }
  }
}

extern "C" void kernel_launch(void* const* d_in, const int* in_sizes, int n_in,
                              void* d_out, int out_size, void* d_ws, size_t ws_size,
                              hipStream_t stream) {
  const float* x = (const float*)d_in[0];
  const float* w_qkv = (const float*)d_in[1];
  const float* b_qkv = (const float*)d_in[2];
  const float* w_proj = (const float*)d_in[3];
  const float* b_proj = (const float*)d_in[4];
  float* outp = (float*)d_out;

  // ---- workspace: bump allocator, 4 KB aligned ----
  char* ws = (char*)d_ws;
  size_t off = 0;
  auto alloc = [&](size_t sz) -> char* {
    char* p = ws + off;
    off = (off + sz + 4095) & ~(size_t)4095;
    return p;
  };
  unsigned* hdr = (unsigned*)alloc(256);   // [0]=max|x| [1]=max|qkv_f| [2]=max|ctx_f|
  float* SWQ = (float*)alloc(QKV_CH * 4);
  float* SWP = (float*)alloc(CH * 4);
  signed char* WQ8 = (signed char*)alloc((size_t)QKV_CH * CH);
  signed char* WP8 = (signed char*)alloc((size_t)CH * CH);
  signed char* X8  = (signed char*)alloc((size_t)(M_ROWS + 128) * CH);
  signed char* Q8  = (signed char*)alloc((size_t)M_ROWS * CH);
  signed char* K8  = (signed char*)alloc((size_t)M_ROWS * CH);
  signed char* VT8 = (signed char*)alloc((size_t)BQ * NH * 64 * VT_ROW);
  signed char* C8  = (signed char*)alloc((size_t)(M_ROWS + 128) * CH);
  int* QKVI = (int*)alloc((size_t)M_ROWS * QKV_CH * 4);
  int* CTXI = (int*)alloc((size_t)M_ROWS * CH * 4);
  (void)ws_size;

  hipMemsetAsync(hdr, 0, 256, stream);
  // 1: fused weight quant + absmax(x)
  k_prep<<<QKV_CH + CH + 1024, 256, 0, stream>>>(x, w_qkv, w_proj, WQ8, SWQ, WP8, SWP, hdr + 0);
  // 2: activation quant
  k_aquant<<<2048, 256, 0, stream>>>(x, NX, hdr, X8);
  // 3: qkv GEMM
  dim3 g1(QKV_CH / 128, (M_ROWS + 127) / 128);
  k_gemm_qkv<<<g1, 256, 0, stream>>>(X8, WQ8, SWQ, b_qkv, hdr, QKVI, hdr + 1);
  // 4: requant (Q/K linear + V LDS-transpose), per-channel constants inline
  k_qkv_requant<<<NQKB + BQ * NH * 10, 256, 0, stream>>>(QKVI, SWQ, hdr, Q8, K8, VT8);
  // 5: attention
  dim3 ga(37, BQ * NH);
  k_attn<<<ga, 256, 0, stream>>>(Q8, K8, VT8, hdr, CTXI, hdr + 2);
  // 6: ctx requant
  k_ctx_requant<<<2048, 256, 0, stream>>>(CTXI, hdr, C8);
  // 7: output GEMM
  dim3 g2(CH / 128, (M_ROWS + 127) / 128);
  k_gemm_out<<<g2, 256, 0, stream>>>(C8, WP8, SWP, b_proj, hdr, outp);
}

// Round 10
// 233.977 us; speedup vs baseline: 3.8272x; 1.0704x over previous
//
#include <hip/hip_runtime.h>
#include <math.h>

// Problem constants
#define BQ 8
#define SEQ 577
#define CH 768
#define NH 12
#define HD 64
#define M_ROWS (BQ * SEQ)      // 4616
#define QKV_CH (3 * CH)        // 2304
#define NX (M_ROWS * CH)       // 3545088
#define EPSF 1.1920929e-07f
#define F2P31 2147483648.0f    // float32(2^31 - 1) rounds to 2^31 -- replicate jnp

#define VT_ROW 640             // Vt row bytes (577 padded, 64B-aligned rows)
#define P_STRIDE 664           // P LDS row stride bytes

typedef __attribute__((ext_vector_type(4))) int i32x4;
typedef struct __align__(16) { long x, y; } L2T;

// shiftmax exp_int: bit-exact replication of reference f32 op sequence.
__device__ __forceinline__ float softmax_e(int svr, int mxr, float x0, float nx0) {
  float xi = (float)(svr - mxr);
  xi = xi + floorf(xi * 0.5f) - floorf(xi * 0.0625f);  // exact pow2 ops on ints
  xi = fmaxf(xi, nx0);
  float qd = floorf(xi / x0);                          // correctly-rounded fdiv, as ref
  float rr = xi - x0 * qd;
  int qi = (int)qd;                                    // in [0,15] for valid lanes
  float p2 = __int_as_float((142 - qi) << 23);         // 2^(15-qi) exact
  float e = floorf((rr * 0.5f - x0) * p2);
  return fmaxf(e, 0.0f);
}

// ---- shared MFMA accumulate: 128x128 block tile, wave w does 64x64, frags from global ----
__device__ __forceinline__ void mfma_gemm_core(
    const signed char* __restrict__ A, const signed char* __restrict__ Bm,
    int arow, int bcol, int c, int q, i32x4 acc[4][4]) {
  for (int k0 = 0; k0 < CH; k0 += 64) {
    L2T af[4], bf[4];
#pragma unroll
    for (int i = 0; i < 4; ++i)
      af[i] = *(const L2T*)(A + (size_t)(arow + i * 16 + c) * CH + k0 + q * 16);
#pragma unroll
    for (int j = 0; j < 4; ++j)
      bf[j] = *(const L2T*)(Bm + (size_t)(bcol + j * 16 + c) * CH + k0 + q * 16);
#pragma unroll
    for (int i = 0; i < 4; ++i)
#pragma unroll
      for (int j = 0; j < 4; ++j) {
        acc[i][j] = __builtin_amdgcn_mfma_i32_16x16x32_i8(af[i].x, bf[j].x, acc[i][j], 0, 0, 0);
        acc[i][j] = __builtin_amdgcn_mfma_i32_16x16x32_i8(af[i].y, bf[j].y, acc[i][j], 0, 0, 0);
      }
  }
}

// ---------------- fused prep: blocks [0,3072) weight-quant rows; [3072,4096) absmax(x) ----
__global__ __launch_bounds__(256) void k_prep(
    const float* __restrict__ x, const float* __restrict__ w_qkv,
    const float* __restrict__ w_proj,
    signed char* __restrict__ WQ8, float* __restrict__ SWQ,
    signed char* __restrict__ WP8, float* __restrict__ SWP,
    unsigned* __restrict__ gmax) {
  __shared__ float red[4];
  int blk = blockIdx.x, tid = threadIdx.x;
  if (blk < QKV_CH + CH) {
    const float* wr; signed char* w8; float* sw; int r;
    if (blk < QKV_CH) { r = blk; wr = w_qkv + (size_t)r * CH; w8 = WQ8 + (size_t)r * CH; sw = SWQ; }
    else { r = blk - QKV_CH; wr = w_proj + (size_t)r * CH; w8 = WP8 + (size_t)r * CH; sw = SWP; }
    float m = 0.f;
    for (int c = tid; c < CH; c += 256) m = fmaxf(m, fabsf(wr[c]));
#pragma unroll
    for (int o = 32; o; o >>= 1) m = fmaxf(m, __shfl_xor(m, o, 64));
    if ((tid & 63) == 0) red[tid >> 6] = m;
    __syncthreads();
    float mm = fmaxf(fmaxf(red[0], red[1]), fmaxf(red[2], red[3]));
    float s = fmaxf(mm / 127.0f, EPSF);
    if (tid == 0) sw[r] = s;
    for (int c = tid; c < CH; c += 256) {
      float q = rintf(wr[c] / s);
      q = fminf(fmaxf(q, -128.f), 127.f);
      w8[c] = (signed char)q;
    }
  } else {
    int ab = blk - (QKV_CH + CH);            // [0,1024)
    float m = 0.f;
    for (int i = ab * 256 + tid; i < NX; i += 1024 * 256) m = fmaxf(m, fabsf(x[i]));
#pragma unroll
    for (int o = 32; o; o >>= 1) m = fmaxf(m, __shfl_xor(m, o, 64));
    if ((tid & 63) == 0) red[tid >> 6] = m;
    __syncthreads();
    if (tid == 0)
      atomicMax(gmax, __float_as_uint(fmaxf(fmaxf(red[0], red[1]), fmaxf(red[2], red[3]))));
  }
}

// ---------------- per-tensor activation quant ----------------
__global__ void k_aquant(const float* __restrict__ x, int n,
                         const unsigned* __restrict__ hdr, signed char* __restrict__ x8) {
  float s = fmaxf(__uint_as_float(hdr[0]) / 127.0f, EPSF);
  int stride = gridDim.x * blockDim.x;
  for (int i = blockIdx.x * blockDim.x + threadIdx.x; i < n; i += stride) {
    float q = rintf(x[i] / s);
    q = fminf(fmaxf(q, -128.f), 127.f);
    x8[i] = (signed char)q;
  }
}

// ---------------- GEMM1 (MFMA): qkv_int = X8*WQ8^T + rint(bias/acc_s); track max|qkv_f| ----
__global__ __launch_bounds__(256) void k_gemm_qkv(
    const signed char* __restrict__ A, const signed char* __restrict__ Bm,
    const float* __restrict__ swq, const float* __restrict__ bias,
    const unsigned* __restrict__ hdr, int* __restrict__ Cq, unsigned* __restrict__ gq) {
  __shared__ float red[4];
  int t = threadIdx.x;
  int lane = t & 63, w = t >> 6;
  int c = lane & 15, q = lane >> 4;
  int arow = blockIdx.y * 128 + (w & 1) * 64;
  int bcol = blockIdx.x * 128 + (w >> 1) * 64;
  i32x4 acc[4][4] = {};
  mfma_gemm_core(A, Bm, arow, bcol, c, q, acc);
  float s_x = fmaxf(__uint_as_float(hdr[0]) / 127.0f, EPSF);
  float lmax = 0.f;
#pragma unroll
  for (int j = 0; j < 4; ++j) {
    int ccol = bcol + j * 16 + c;
    float accs = s_x * swq[ccol];
    int bint = (int)rintf(bias[ccol] / accs);
#pragma unroll
    for (int i = 0; i < 4; ++i)
#pragma unroll
      for (int r = 0; r < 4; ++r) {
        int rr = arow + i * 16 + q * 4 + r;
        if (rr < M_ROWS) {
          int qv = acc[i][j][r] + bint;
          Cq[(size_t)rr * QKV_CH + ccol] = qv;
          lmax = fmaxf(lmax, fabsf((float)qv * accs));
        }
      }
  }
#pragma unroll
  for (int off = 32; off; off >>= 1) lmax = fmaxf(lmax, __shfl_xor(lmax, off, 64));
  if (lane == 0) red[w] = lmax;
  __syncthreads();
  if (t == 0)
    atomicMax(gq, __float_as_uint(fmaxf(fmaxf(red[0], red[1]), fmaxf(red[2], red[3]))));
}

// ---- requant: blocks [0,870) Q/K col-fixed threads; [870,1830) V LDS-transpose tiles ----
#define QK_BLKS 870   // 6 col-chunks x 145 row-chunks
__global__ __launch_bounds__(256) void k_qkv_requant(
    const int* __restrict__ Cq, const float* __restrict__ swq,
    const unsigned* __restrict__ hdr,
    signed char* __restrict__ Q8, signed char* __restrict__ K8,
    signed char* __restrict__ VT8) {
  float s_x = fmaxf(__uint_as_float(hdr[0]) / 127.0f, EPSF);
  float s_qkv = fmaxf(__uint_as_float(hdr[1]) / 127.0f, EPSF);
  int blk = blockIdx.x, tid = threadIdx.x;
  if (blk < QK_BLKS) {
    int bx = blk % 6, by = blk / 6;
    int o = bx * 256 + tid;                  // fixed channel per thread, [0,1536)
    float accs = s_x * swq[o];
    float ns = accs / s_qkv;
    int e; float f = frexpf(ns, &e);
    float mm = floorf(f * F2P31 + 0.5f);     // hoisted: once per thread
    float pw = __int_as_float((e + 96) << 23);  // 2^(e-31) exact
    int isK = (o >= CH);
    int rem = o - (isK ? CH : 0);
    int h = rem >> 6, d = rem & 63;
    signed char* dstb = isK ? K8 : Q8;
    int bn0 = by * 32;
    int bnend = min(bn0 + 32, M_ROWS);
    for (int bn = bn0; bn < bnend; ++bn) {
      int qv = Cq[(size_t)bn * QKV_CH + o];  // wave reads 256B contiguous
      float qf = (float)qv * accs;
      float z = rintf(qf / accs);
      float t8 = rintf((z * mm) * pw);
      t8 = fminf(fmaxf(t8, -128.f), 127.f);
      int b = bn / SEQ, n = bn - b * SEQ;
      dstb[(((size_t)(b * NH + h) * SEQ + n) << 6) + d] = (signed char)t8;
    }
  } else {
    // V: one (bh, 64-n) tile per block, transpose through LDS -> coalesced VT8 writes
    __shared__ signed char VTt[64 * 68];
    int vt = blk - QK_BLKS;                  // [0, 960)
    int bh = vt / 10, n0 = (vt - bh * 10) * 64;
    int b = bh / NH, h = bh - b * NH;
    int od = tid & 63;                       // d within head
    int o = 2 * CH + h * 64 + od;
    float accs = s_x * swq[o];
    float ns = accs / s_qkv;
    int e; float f = frexpf(ns, &e);
    float mm = floorf(f * F2P31 + 0.5f);
    float pw = __int_as_float((e + 96) << 23);
    int nr = tid >> 6;                       // 0..3
    for (int p = 0; p < 16; ++p) {
      int nl = nr * 16 + p;
      int n = n0 + nl;
      signed char v = 0;
      if (n < SEQ) {
        int qv = Cq[(size_t)(b * SEQ + n) * QKV_CH + o];
        float qf = (float)qv * accs;
        float z = rintf(qf / accs);
        float t8 = rintf((z * mm) * pw);
        t8 = fminf(fmaxf(t8, -128.f), 127.f);
        v = (signed char)t8;
      }
      VTt[od * 68 + nl] = v;
    }
    __syncthreads();
    int w16 = tid & 15, dr = tid >> 4;
#pragma unroll
    for (int pp = 0; pp < 4; ++pp) {
      int d = pp * 16 + dr;
      int val = *(const int*)&VTt[d * 68 + w16 * 4];
      *(int*)(VT8 + (size_t)bh * (64 * VT_ROW) + (size_t)d * VT_ROW + n0 + w16 * 4) = val;
    }
  }
}

// ---- attention: 1-D grid 3552, XCD-pinned (all 37 qt of a bh on one XCD); 4 waves ----
__global__ __launch_bounds__(256, 4) void k_attn(
    const signed char* __restrict__ Q8, const signed char* __restrict__ K8,
    const signed char* __restrict__ VT8, const unsigned* __restrict__ hdr,
    int* __restrict__ ctxi, unsigned* __restrict__ gctx) {
  __shared__ unsigned char P[16 * P_STRIDE];   // probs [row][m]
  __shared__ int Rmax[4][16];
  __shared__ double Rsum[4][16];
  __shared__ float Rav[4];
  int tid = threadIdx.x;
  int t = tid & 63, wid = tid >> 6;
  // XCD-aware swizzle (round-robin dispatch heuristic; perf-only, any mapping is correct):
  int lin = blockIdx.x;
  int j = lin >> 3;
  int bh = (lin & 7) * 12 + j / 37;   // 8 XCDs x 12 bh each
  int qt = j % 37;
  int b = bh / NH, h = bh - b * NH;
  int col = t & 15, q4 = t >> 4;
  {
    int r = tid >> 4, w4 = tid & 15;
    *(int*)&P[r * P_STRIDE + 576 + (w4 << 2)] = 0;
  }
  const signed char* Qb = Q8 + (((size_t)bh * SEQ + qt * 16 + col) << 6);
  long qa0 = *(const long*)(Qb + q4 * 8);
  long qa1 = *(const long*)(Qb + 32 + q4 * 8);
  const signed char* Kb = K8 + ((size_t)bh * SEQ << 6);
  int kt0 = (wid == 0) ? 0 : 10 + (wid - 1) * 9;
  int ktn = (wid == 0) ? 10 : 9;
  i32x4 sv[10];
  int mx[4] = {-2147483647 - 1, -2147483647 - 1, -2147483647 - 1, -2147483647 - 1};
#pragma unroll
  for (int u = 0; u < 10; ++u) {
    if (u < ktn) {
      int kt = kt0 + u;
      const signed char* kr = Kb + ((size_t)(kt * 16 + col) << 6);
      long kb0 = *(const long*)(kr + q4 * 8);
      long kb1 = *(const long*)(kr + 32 + q4 * 8);
      i32x4 a = {0, 0, 0, 0};
      a = __builtin_amdgcn_mfma_i32_16x16x32_i8(qa0, kb0, a, 0, 0, 0);
      a = __builtin_amdgcn_mfma_i32_16x16x32_i8(qa1, kb1, a, 0, 0, 0);
      sv[u] = a;
      bool valid = (kt < 36) | (col < 1);
#pragma unroll
      for (int r = 0; r < 4; ++r)
        if (valid) mx[r] = max(mx[r], a[r]);
    }
  }
#pragma unroll
  for (int r = 0; r < 4; ++r) {
    mx[r] = max(mx[r], __shfl_xor(mx[r], 1, 64));
    mx[r] = max(mx[r], __shfl_xor(mx[r], 2, 64));
    mx[r] = max(mx[r], __shfl_xor(mx[r], 4, 64));
    mx[r] = max(mx[r], __shfl_xor(mx[r], 8, 64));
  }
  if (col == 0) {
#pragma unroll
    for (int r = 0; r < 4; ++r) Rmax[wid][q4 * 4 + r] = mx[r];
  }
  __syncthreads();
#pragma unroll
  for (int r = 0; r < 4; ++r) {
    int row = q4 * 4 + r;
    mx[r] = max(max(Rmax[0][row], Rmax[1][row]), max(Rmax[2][row], Rmax[3][row]));
  }
  float s_qkv = fmaxf(__uint_as_float(hdr[1]) / 127.0f, EPSF);
  float s_attn = (s_qkv * s_qkv) * 0.125f;
  float x0 = floorf(-1.0f / s_attn);
  float nx0 = 15.0f * x0;
  double ds[4] = {0.0, 0.0, 0.0, 0.0};
#pragma unroll
  for (int u = 0; u < 10; ++u) {
    if (u < ktn) {
      int kt = kt0 + u;
      bool valid = (kt < 36) | (col < 1);
#pragma unroll
      for (int r = 0; r < 4; ++r) {
        float e = softmax_e(sv[u][r], mx[r], x0, nx0);
        e = valid ? e : 0.0f;
        ds[r] += (double)e;   // exact integers -> order-free
        sv[u][r] = __float_as_int(e);
      }
    }
  }
#pragma unroll
  for (int r = 0; r < 4; ++r) {
    ds[r] += __shfl_xor(ds[r], 1, 64);
    ds[r] += __shfl_xor(ds[r], 2, 64);
    ds[r] += __shfl_xor(ds[r], 4, 64);
    ds[r] += __shfl_xor(ds[r], 8, 64);
  }
  if (col == 0) {
#pragma unroll
    for (int r = 0; r < 4; ++r) Rsum[wid][q4 * 4 + r] = ds[r];
  }
  __syncthreads();
  float fac[4];
#pragma unroll
  for (int r = 0; r < 4; ++r) {
    int row = q4 * 4 + r;
    double d = ((Rsum[0][row] + Rsum[1][row]) + Rsum[2][row]) + Rsum[3][row];
    float esum = fminf((float)d, F2P31);
    fac[r] = floorf(F2P31 / esum);
  }
#pragma unroll
  for (int u = 0; u < 10; ++u) {
    if (u < ktn) {
      int kt = kt0 + u;
#pragma unroll
      for (int r = 0; r < 4; ++r) {
        float e = __int_as_float(sv[u][r]);
        int p = (int)floorf((e * fac[r]) * 5.9604644775390625e-08f);  // /2^24 exact
        P[(q4 * 4 + r) * P_STRIDE + kt * 16 + col] = (unsigned char)p;
      }
    }
  }
  __syncthreads();
  const signed char* Vb = VT8 + (size_t)bh * (64 * VT_ROW);
  i32x4 acc = {0, 0, 0, 0};
  for (int mc = 0; mc < 20; ++mc) {
    long pa = *(const long*)&P[col * P_STRIDE + mc * 32 + q4 * 8];
    long vb = *(const long*)(Vb + (size_t)(wid * 16 + col) * VT_ROW + mc * 32 + q4 * 8);
    acc = __builtin_amdgcn_mfma_i32_16x16x32_i8(pa, vb, acc, 0, 0, 0);
  }
  float pre_s = 0.0078125f * s_qkv;
  float avmax = 0.f;
#pragma unroll
  for (int r = 0; r < 4; ++r) {
    int n = qt * 16 + q4 * 4 + r;
    if (n < SEQ) {
      int cacc = acc[r];
      ctxi[((size_t)(b * SEQ + n)) * CH + h * 64 + wid * 16 + col] = cacc;
      avmax = fmaxf(avmax, fabsf((float)cacc * pre_s));
    }
  }
#pragma unroll
  for (int off = 32; off; off >>= 1) avmax = fmaxf(avmax, __shfl_xor(avmax, off, 64));
  if (t == 0) Rav[wid] = avmax;
  __syncthreads();
  if (tid == 0)
    atomicMax(gctx, __float_as_uint(fmaxf(fmaxf(Rav[0], Rav[1]), fmaxf(Rav[2], Rav[3]))));
}

// ---------------- requant ctx -> int8 (vectorized x4) ----------------
__global__ void k_ctx_requant(const int* __restrict__ ctxi, const unsigned* __restrict__ hdr,
                              signed char* __restrict__ C8) {
  float s_qkv = fmaxf(__uint_as_float(hdr[1]) / 127.0f, EPSF);
  float pre_s = 0.0078125f * s_qkv;
  float s_ctx = fmaxf(__uint_as_float(hdr[2]) / 127.0f, EPSF);
  float ns = pre_s / s_ctx;
  int e;
  float f = frexpf(ns, &e);
  float mm = floorf(f * F2P31 + 0.5f);
  float pw = exp2f((float)e - 31.0f);
  int total4 = (M_ROWS * CH) / 4;
  int stride = gridDim.x * blockDim.x;
  const int4* src = (const int4*)ctxi;
  int* dst = (int*)C8;
  for (int i = blockIdx.x * blockDim.x + threadIdx.x; i < total4; i += stride) {
    int4 v = src[i];
    int pk = 0;
#pragma unroll
    for (int u = 0; u < 4; ++u) {
      int cv = (u == 0) ? v.x : (u == 1) ? v.y : (u == 2) ? v.z : v.w;
      float cf = (float)cv * pre_s;
      float z = rintf(cf / pre_s);
      float t8 = rintf((z * mm) * pw);
      t8 = fminf(fmaxf(t8, -128.f), 127.f);
      pk |= ((int)(signed char)t8 & 0xff) << (u * 8);
    }
    dst[i] = pk;
  }
}

// ---------------- GEMM2 (MFMA): out = (C8*WP8^T + rint(b/out_s)) * out_s ----------------
__global__ __launch_bounds__(256) void k_gemm_out(
    const signed char* __restrict__ A, const signed char* __restrict__ Bm,
    const float* __restrict__ swp, const float* __restrict__ bias,
    const unsigned* __restrict__ hdr, float* __restrict__ outp) {
  int t = threadIdx.x;
  int lane = t & 63, w = t >> 6;
  int c = lane & 15, q = lane >> 4;
  int arow = blockIdx.y * 128 + (w & 1) * 64;
  int bcol = blockIdx.x * 128 + (w >> 1) * 64;
  i32x4 acc[4][4] = {};
  mfma_gemm_core(A, Bm, arow, bcol, c, q, acc);
  float s_ctx = fmaxf(__uint_as_float(hdr[2]) / 127.0f, EPSF);
#pragma unroll
  for (int j = 0; j < 4; ++j) {
    int ccol = bcol + j * 16 + c;
    float outs = s_ctx * swp[ccol];
    int bint = (int)rintf(bias[ccol] / outs);
#pragma unroll
    for (int i = 0; i < 4; ++i)
#pragma unroll
      for (int r = 0; r < 4; ++r) {
        int rr = arow + i * 16 + q * 4 + r;
        if (rr < M_ROWS)
          outp[(size_t)rr * CH + ccol] = (float)(acc[i][j][r] + bint) * outs;
      }
  }
}

extern "C" void kernel_launch(void* const* d_in, const int* in_sizes, int n_in,
                              void* d_out, int out_size, void* d_ws, size_t ws_size,
                              hipStream_t stream) {
  const float* x = (const float*)d_in[0];
  const float* w_qkv = (const float*)d_in[1];
  const float* b_qkv = (const float*)d_in[2];
  const float* w_proj = (const float*)d_in[3];
  const float* b_proj = (const float*)d_in[4];
  float* outp = (float*)d_out;

  // ---- workspace: bump allocator, 4 KB aligned ----
  char* ws = (char*)d_ws;
  size_t off = 0;
  auto alloc = [&](size_t sz) -> char* {
    char* p = ws + off;
    off = (off + sz + 4095) & ~(size_t)4095;
    return p;
  };
  unsigned* hdr = (unsigned*)alloc(256);   // [0]=max|x| [1]=max|qkv_f| [2]=max|ctx_f|
  float* SWQ = (float*)alloc(QKV_CH * 4);
  float* SWP = (float*)alloc(CH * 4);
  signed char* WQ8 = (signed char*)alloc((size_t)QKV_CH * CH);
  signed char* WP8 = (signed char*)alloc((size_t)CH * CH);
  signed char* X8  = (signed char*)alloc((size_t)(M_ROWS + 128) * CH);
  signed char* Q8  = (signed char*)alloc((size_t)M_ROWS * CH);
  signed char* K8  = (signed char*)alloc((size_t)M_ROWS * CH);
  signed char* VT8 = (signed char*)alloc((size_t)BQ * NH * 64 * VT_ROW);
  signed char* C8  = (signed char*)alloc((size_t)(M_ROWS + 128) * CH);
  int* QKVI = (int*)alloc((size_t)M_ROWS * QKV_CH * 4);
  int* CTXI = (int*)alloc((size_t)M_ROWS * CH * 4);
  (void)ws_size;

  hipMemsetAsync(hdr, 0, 256, stream);
  // 1: fused weight quant + absmax(x)
  k_prep<<<QKV_CH + CH + 1024, 256, 0, stream>>>(x, w_qkv, w_proj, WQ8, SWQ, WP8, SWP, hdr + 0);
  // 2: activation quant
  k_aquant<<<2048, 256, 0, stream>>>(x, NX, hdr, X8);
  // 3: qkv GEMM
  dim3 g1(QKV_CH / 128, (M_ROWS + 127) / 128);
  k_gemm_qkv<<<g1, 256, 0, stream>>>(X8, WQ8, SWQ, b_qkv, hdr, QKVI, hdr + 1);
  // 4: requant (Q/K col-fixed + V LDS-transpose)
  k_qkv_requant<<<QK_BLKS + BQ * NH * 10, 256, 0, stream>>>(QKVI, SWQ, hdr, Q8, K8, VT8);
  // 5: attention (XCD-pinned 1-D grid)
  k_attn<<<37 * BQ * NH, 256, 0, stream>>>(Q8, K8, VT8, hdr, CTXI, hdr + 2);
  // 6: ctx requant
  k_ctx_requant<<<1024, 256, 0, stream>>>(CTXI, hdr, C8);
  // 7: output GEMM
  dim3 g2(CH / 128, (M_ROWS + 127) / 128);
  k_gemm_out<<<g2, 256, 0, stream>>>(C8, WP8, SWP, b_proj, hdr, outp);
}